// Round 13
// baseline (271.877 us; speedup 1.0000x reference)
//
#include <hip/hip_runtime.h>
#include <hip/hip_bf16.h>

#define HID 1024
#define NH 16
#define HD 64
#define SEQ 2048
#define NB 2
#define NTOK (NB * SEQ)  // 4096

typedef __attribute__((ext_vector_type(8))) short bf16x8;
typedef __attribute__((ext_vector_type(4))) float f32x4;
typedef __attribute__((ext_vector_type(4))) unsigned u32x4;

// softmax runs in log2 domain (native v_exp_f32 = 2^x)
#define QSCALE 0.18033688011112042f   // 0.125 * log2(e)
#define MASKSCALE 1.4426950408889634f

#define MFMA16(a, b, c) __builtin_amdgcn_mfma_f32_16x16x32_bf16((a), (b), (c), 0, 0, 0)

__device__ __forceinline__ unsigned short f2bf(float f) {
    unsigned u = __builtin_bit_cast(unsigned, f);
    u += 0x7FFFu + ((u >> 16) & 1u);   // RNE
    return (unsigned short)(u >> 16);
}
__device__ __forceinline__ unsigned cvtpk(float a, float b) {
    unsigned r;
    asm("v_cvt_pk_bf16_f32 %0, %1, %2" : "=v"(r) : "v"(a), "v"(b));
    return r;
}
__device__ __forceinline__ void gload_lds16(const unsigned short* g, unsigned short* l) {
    __builtin_amdgcn_global_load_lds(
        (const __attribute__((address_space(1))) unsigned int*)g,
        (__attribute__((address_space(3))) unsigned int*)l, 16, 0, 0);
}

// ---------------- merged conversion + flags kernel (6 jobs, one launch) ----------------
__global__ __launch_bounds__(256) void cvt_all(
    const float* __restrict__ xq, const float* __restrict__ xk,
    const float* __restrict__ Wq, const float* __restrict__ Wk, const float* __restrict__ Wv,
    const float* __restrict__ mask,
    unsigned short* __restrict__ dxq, unsigned short* __restrict__ dxk,
    unsigned short* __restrict__ dwq, unsigned short* __restrict__ dwk,
    unsigned short* __restrict__ dwv, int* __restrict__ flags) {
    const int id = blockIdx.x;
    if (id >= 11264) {   // mask -> per-64x64-tile all-ones flags
        const int lane = threadIdx.x & 63;
        int i = ((id - 11264) * 256 + threadIdx.x) * 4;
        float4 v = *(const float4*)(mask + i);
        bool ok = (v.x == 1.0f) && (v.y == 1.0f) && (v.z == 1.0f) && (v.w == 1.0f);
        unsigned long long bal = __ballot(ok);
        int g = lane >> 4;     // each 16-lane group covers 64 contiguous k = one k-tile
        if ((lane & 15) == 0) {
            unsigned m16 = (unsigned)(bal >> (g * 16)) & 0xFFFFu;
            if (m16 != 0xFFFFu) {
                int b = i >> 22;               // SEQ*SEQ = 2^22
                int rem = i & 4194303;
                int q = rem >> 11, k = rem & 2047;
                atomicAnd(&flags[(b << 10) + ((q >> 6) << 5) + (k >> 6)], 0);
            }
        }
        return;
    }
    const float* src;
    unsigned short* dst;
    int base;
    float scale = 1.0f;
    if (id < 4096)       { src = xq; dst = dxq; base = 0; }
    else if (id < 8192)  { src = xk; dst = dxk; base = 4096; }
    else if (id < 9216)  { src = Wq; dst = dwq; base = 8192; scale = QSCALE; }
    else if (id < 10240) { src = Wk; dst = dwk; base = 9216; }
    else                 { src = Wv; dst = dwv; base = 10240; }
    int i = ((id - base) * 256 + threadIdx.x) * 4;
    float4 v = *(const float4*)(src + i);
    ushort4 o;
    o.x = f2bf(v.x * scale); o.y = f2bf(v.y * scale);
    o.z = f2bf(v.z * scale); o.w = f2bf(v.w * scale);
    *(ushort4*)(dst + i) = o;
}

// ---------------- QKV projection GEMMs (round-10 proven config; sigma removed) ------
// 768 blocks (flat XCD-swizzled = 3 blocks/CU), 128x128 tile, 4 waves, BK=32,
// 3-buffer rotation with counted vmcnt(4) + raw s_barrier. XOR-swizzled LDS.
__global__ __launch_bounds__(256, 3) void proj_gemm(
    const unsigned short* __restrict__ xq, const unsigned short* __restrict__ xk,
    const unsigned short* __restrict__ wq, const unsigned short* __restrict__ wk,
    const unsigned short* __restrict__ wv,
    const float* __restrict__ bq, const float* __restrict__ bk, const float* __restrict__ bv,
    unsigned short* __restrict__ Qh, unsigned short* __restrict__ Kh,
    unsigned short* __restrict__ Vt) {
    __shared__ __align__(16) unsigned short As[3][128 * 32];   // 24 KB
    __shared__ __align__(16) unsigned short Bs[3][128 * 32];   // 24 KB

    const int id = blockIdx.x;
    const int xid = (id & 7) * 96 + (id >> 3);   // 768 = 8*96, bijective XCD swizzle
    const unsigned short *A, *B;
    const float* bias;
    float bsc = 1.0f;
    unsigned short* out;
    int mt, nt;
    bool tr = false;
    if (xid < 256)      { A = xq; B = wq; bias = bq; bsc = QSCALE; out = Qh;
                          mt = xid >> 3; nt = xid & 7; }
    else if (xid < 512) { A = xk; B = wk; bias = bk; out = Kh;
                          mt = (xid - 256) >> 3; nt = (xid - 256) & 7; }
    else                { A = wv; B = xk; bias = bv; out = Vt; tr = true;
                          mt = (xid - 512) & 7; nt = (xid - 512) >> 3; }
    const int m0 = mt * 128, n0 = nt * 128;
    const int tid = threadIdx.x, wave = tid >> 6, lane = tid & 63;
    const int wr = (wave >> 1) * 64, wc = (wave & 1) * 64;
    const int fr = lane & 15, hi = lane >> 4;

    const int uswz = (hi ^ ((fr >> 1) & 3)) << 3;
    const int abase = (wr + fr) * 32 + uswz;
    const int bbase = (wc + fr) * 32 + uswz;

    const int srow = wave * 16 + (lane >> 2);
    const int sunit = (lane & 3) ^ ((lane >> 3) & 3);
    const unsigned short* Asrc = A + (size_t)(m0 + srow) * HID + sunit * 8;
    const unsigned short* Bsrc = B + (size_t)(n0 + srow) * HID + sunit * 8;

    unsigned short *cA = As[0], *nA = As[1], *fA = As[2];
    unsigned short *cB = Bs[0], *nB = Bs[1], *fB = Bs[2];

    f32x4 acc[4][4] = {};

#define PSTG(t, ap, bp)                                                          \
    do {                                                                         \
        gload_lds16(Asrc + (t) * 32, (ap) + wave * 512);                         \
        gload_lds16(Asrc + (size_t)64 * HID + (t) * 32, (ap) + 2048 + wave * 512); \
        gload_lds16(Bsrc + (t) * 32, (bp) + wave * 512);                         \
        gload_lds16(Bsrc + (size_t)64 * HID + (t) * 32, (bp) + 2048 + wave * 512); \
    } while (0)

    PSTG(0, cA, cB);
    PSTG(1, nA, nB);

    for (int t = 0; t < 32; ++t) {
        if (t < 31) asm volatile("s_waitcnt vmcnt(4)" ::: "memory");  // own stage(t) done
        else        asm volatile("s_waitcnt vmcnt(0)" ::: "memory");
        __builtin_amdgcn_s_barrier();      // everyone's stage(t) landed; buf(t-1) free
        if (t < 30) PSTG(t + 2, fA, fB);   // into the buffer read at t-1

        bf16x8 af[4], bfr[4];
#pragma unroll
        for (int i = 0; i < 4; ++i) af[i] = *(const bf16x8*)&cA[abase + i * 512];
#pragma unroll
        for (int j = 0; j < 4; ++j) bfr[j] = *(const bf16x8*)&cB[bbase + j * 512];
        __builtin_amdgcn_s_setprio(1);
#pragma unroll
        for (int i = 0; i < 4; ++i)
#pragma unroll
            for (int j = 0; j < 4; ++j)
                acc[i][j] = MFMA16(af[i], bfr[j], acc[i][j]);
        __builtin_amdgcn_s_setprio(0);

        unsigned short* ta = cA; cA = nA; nA = fA; fA = ta;
        unsigned short* tb = cB; cB = nB; nB = fB; fB = tb;
    }
#undef PSTG

#pragma unroll
    for (int i = 0; i < 4; ++i)
#pragma unroll
        for (int j = 0; j < 4; ++j)
#pragma unroll
            for (int r = 0; r < 4; ++r) {
                int row = m0 + wr + i * 16 + hi * 4 + r;   // C/D: row=(lane>>4)*4+reg
                int col = n0 + wc + j * 16 + fr;           //      col=lane&15
                float v = acc[i][j][r];
                if (!tr) {
                    v += bsc * bias[col];
                    int b = row >> 11, l = row & 2047, hh = col >> 6, d = col & 63;
                    out[(((size_t)(b * NH + hh)) * SEQ + l) * HD + d] = f2bf(v);
                } else {
                    v += bias[row];
                    int b = col >> 11, ll = col & 2047, hh = row >> 6, d = row & 63;
                    // NATURAL k layout (split-K flash reads slices directly; no sigma)
                    out[(((size_t)(b * NH + hh)) * HD + d) * SEQ + ll] = f2bf(v);
                }
            }
}

// ---------------- flash attention (split-K across waves) ----------------
// grid 512 (XCD-clustered bh), 4 waves; block = 128 q. Wave w owns k-rows
// [w*16, w*16+16) of EVERY tile for all 128 q (Q in registers) -> per pair of
// tiles each wave reads only 4 K b128 + 8 V b64 (4x less DS). PV pairs two
// tiles' P into one K=32 MFMA; slot map handled by the V A-frag read pattern
// (natural Vt layout). 4-buffer ring, one barrier per 2 tiles (R10-proven).
// Epilogue: cross-wave LDS reduction (2 halves), wave 0 normalizes + stores.
__global__ __launch_bounds__(256, 2) void flash_attn(
    const unsigned short* __restrict__ Qh, const unsigned short* __restrict__ Kh,
    const unsigned short* __restrict__ Vt, const float* __restrict__ mask,
    const int* __restrict__ flags, float* __restrict__ out) {
    __shared__ __align__(16) unsigned short LB[8][64 * 64];   // 64 KB: K bufs 0-3, V bufs 4-7

    const int tid = threadIdx.x, wave = tid >> 6, lane = tid & 63;
    const int id = blockIdx.x;                       // 0..511
    const int bh = (id & 7) * 4 + ((id >> 3) & 3);   // XCD-clustered
    const int qi = id >> 5;                          // 128-q tile index 0..15
    const int b = bh >> 4, h = bh & 15;
    const size_t hoff = (size_t)bh * SEQ * HD;
    const int fr = lane & 15, hi = lane >> 4;
    const int f7 = fr & 7;

    // Q in registers: 8 qsub x 2 dblk B-frags (col=q=lane&15, d=dblk*32+hi*8)
    bf16x8 qf0[8], qf1[8];
#pragma unroll
    for (int qs = 0; qs < 8; ++qs) {
        const size_t qrow = hoff + (size_t)(qi * 128 + qs * 16 + fr) * HD;
        qf0[qs] = *(const bf16x8*)&Qh[qrow + hi * 8];
        qf1[qs] = *(const bf16x8*)&Qh[qrow + 32 + hi * 8];
    }

    const float* mbase = mask + (size_t)b * SEQ * SEQ;
    // flag bitmasks for the two 64-q halves of this block
    const int* fr0 = flags + (b << 10) + ((qi * 2) << 5);
    const int* fr1 = flags + (b << 10) + ((qi * 2 + 1) << 5);
    int fv0 = fr0[lane & 31], fv1 = fr1[lane & 31];
    const unsigned long long bm0 = __ballot(fv0 != 0);
    const unsigned long long bm1 = __ballot(fv1 != 0);

    // staging: linear LDS dest, inverse-swizzled global source (key = row&7)
    const int srow = wave * 8 + (lane >> 3);
    const int sch = (lane & 7) ^ (srow & 7);
    const unsigned short* kbase = Kh + hoff + (size_t)srow * HD + (sch << 3);
    const unsigned short* vbase = Vt + hoff + (size_t)srow * SEQ + (sch << 3);

    f32x4 acc[8][4] = {};     // [qsub][dsub]
    float lp[8] = {};         // per-lane l partials (this lane's 4 k-rows per slice)

    // frag read offsets (shorts). K: row = w*16+fr, unit (dblk*4+hi)^(fr&7).
    const int krow = (wave * 16 + fr) * 64;
    const int ku0 = ((hi) ^ f7) << 3;
    const int ku1 = ((4 + hi) ^ f7) << 3;
    // V: row = dsub*16+fr, unit (wave*2 + (hi>>1))^(fr&7), half (hi&1)
    const int vu = (((wave * 2 + (hi >> 1)) ^ f7) << 3) + ((hi & 1) << 2);

#define STG(t, ki, vi)                                                                \
    do {                                                                              \
        gload_lds16(kbase + (size_t)(t) * 64 * HD, LB[ki] + (wave * 8) * 64);         \
        gload_lds16(kbase + (size_t)((t) * 64 + 32) * HD, LB[ki] + (wave * 8 + 32) * 64); \
        gload_lds16(vbase + (t) * 64, LB[vi] + (wave * 8) * 64);                      \
        gload_lds16(vbase + (size_t)32 * SEQ + (t) * 64, LB[vi] + (wave * 8 + 32) * 64); \
    } while (0)

#define FPAIR(kA, vA, kB, vB, tt)                                                     \
    do {                                                                              \
        bf16x8 ka0 = *(const bf16x8*)&LB[kA][krow + ku0];                             \
        bf16x8 ka1 = *(const bf16x8*)&LB[kA][krow + ku1];                             \
        bf16x8 kb0 = *(const bf16x8*)&LB[kB][krow + ku0];                             \
        bf16x8 kb1 = *(const bf16x8*)&LB[kB][krow + ku1];                             \
        bf16x8 vf[4];                                                                 \
        _Pragma("unroll")                                                             \
        for (int ds = 0; ds < 4; ++ds) {                                              \
            const int off = (ds * 16 + fr) * 64 + vu;                                 \
            uint2 va = *(const uint2*)&LB[vA][off];                                   \
            uint2 vb = *(const uint2*)&LB[vB][off];                                   \
            u32x4 vv = {va.x, va.y, vb.x, vb.y};                                      \
            vf[ds] = __builtin_bit_cast(bf16x8, vv);                                  \
        }                                                                             \
        _Pragma("unroll")                                                             \
        for (int qs = 0; qs < 8; ++qs) {                                              \
            f32x4 st = {0.f, 0.f, 0.f, 0.f}, su = {0.f, 0.f, 0.f, 0.f};               \
            __builtin_amdgcn_s_setprio(1);                                            \
            st = MFMA16(ka0, qf0[qs], st);                                            \
            st = MFMA16(ka1, qf1[qs], st);                                            \
            su = MFMA16(kb0, qf0[qs], su);                                            \
            su = MFMA16(kb1, qf1[qs], su);                                            \
            __builtin_amdgcn_s_setprio(0);                                            \
            const unsigned long long bms = (qs < 4) ? bm0 : bm1;                      \
            if (!((bms >> (tt)) & 1) || !((bms >> ((tt) + 1)) & 1)) {                 \
                const int qq = qi * 128 + qs * 16 + fr;                               \
                const float* mrow = mbase + (size_t)qq * SEQ + wave * 16 + hi * 4;    \
                float4 ma = *(const float4*)&mrow[(tt) * 64];                         \
                float4 mbv = *(const float4*)&mrow[((tt) + 1) * 64];                  \
                st[0] += (1.f - ma.x) * (-10000.f * MASKSCALE);                       \
                st[1] += (1.f - ma.y) * (-10000.f * MASKSCALE);                       \
                st[2] += (1.f - ma.z) * (-10000.f * MASKSCALE);                       \
                st[3] += (1.f - ma.w) * (-10000.f * MASKSCALE);                       \
                su[0] += (1.f - mbv.x) * (-10000.f * MASKSCALE);                      \
                su[1] += (1.f - mbv.y) * (-10000.f * MASKSCALE);                      \
                su[2] += (1.f - mbv.z) * (-10000.f * MASKSCALE);                      \
                su[3] += (1.f - mbv.w) * (-10000.f * MASKSCALE);                      \
            }                                                                         \
            _Pragma("unroll")                                                         \
            for (int r = 0; r < 4; ++r) {                                             \
                st[r] = __builtin_amdgcn_exp2f(st[r]);                                \
                su[r] = __builtin_amdgcn_exp2f(su[r]);                                \
            }                                                                         \
            lp[qs] += ((st[0] + st[1]) + (st[2] + st[3])) +                           \
                      ((su[0] + su[1]) + (su[2] + su[3]));                            \
            u32x4 pw = {cvtpk(st[0], st[1]), cvtpk(st[2], st[3]),                     \
                        cvtpk(su[0], su[1]), cvtpk(su[2], su[3])};                    \
            bf16x8 pb = __builtin_bit_cast(bf16x8, pw);                               \
            __builtin_amdgcn_s_setprio(1);                                            \
            _Pragma("unroll")                                                         \
            for (int ds = 0; ds < 4; ++ds)                                            \
                acc[qs][ds] = MFMA16(vf[ds], pb, acc[qs][ds]);                        \
            __builtin_amdgcn_s_setprio(0);                                            \
        }                                                                             \
    } while (0)

    STG(0, 0, 4);
    STG(1, 1, 5);

    for (int ii = 0; ii < 8; ++ii) {
        const int t0 = ii * 4;
        asm volatile("s_waitcnt vmcnt(0)" ::: "memory");   // prior stages landed
        __builtin_amdgcn_s_barrier();                      // all landed; bufs 2,3 free
        STG(t0 + 2, 2, 6);
        STG(t0 + 3, 3, 7);
        FPAIR(0, 4, 1, 5, t0);
        asm volatile("s_waitcnt vmcnt(0)" ::: "memory");
        __builtin_amdgcn_s_barrier();
        if (ii < 7) {
            STG(t0 + 4, 0, 4);
            STG(t0 + 5, 1, 5);
        }
        FPAIR(2, 6, 3, 7, t0 + 2);
    }
#undef STG
#undef FPAIR

    // ---- cross-wave reduction: waves 1-3 write acc+l, wave 0 adds + stores ----
    __builtin_amdgcn_s_barrier();   // all waves done reading K/V buffers
    float* R = (float*)&LB[0][0];   // 64 KB scratch (16384 floats)
#pragma unroll
    for (int hf = 0; hf < 2; ++hf) {
        if (wave >= 1) {
            const int wb = (wave - 1) * 4352;
#pragma unroll
            for (int qs2 = 0; qs2 < 4; ++qs2) {
                const int qs = hf * 4 + qs2;
#pragma unroll
                for (int ds = 0; ds < 4; ++ds)
                    *(f32x4*)&R[wb + (qs2 * 4 + ds) * 256 + lane * 4] = acc[qs][ds];
                R[wb + 4096 + qs2 * 64 + lane] = lp[qs];
            }
        }
        __builtin_amdgcn_s_barrier();
        if (wave == 0) {
#pragma unroll
            for (int qs2 = 0; qs2 < 4; ++qs2) {
                const int qs = hf * 4 + qs2;
                float ls = lp[qs];
#pragma unroll
                for (int w = 0; w < 3; ++w) ls += R[w * 4352 + 4096 + qs2 * 64 + lane];
                ls += __shfl_xor(ls, 16);
                ls += __shfl_xor(ls, 32);
                const float rinv = 1.0f / ls;
                const int qq = qi * 128 + qs * 16 + fr;
#pragma unroll
                for (int ds = 0; ds < 4; ++ds) {
                    f32x4 a = acc[qs][ds];
#pragma unroll
                    for (int w = 0; w < 3; ++w)
                        a += *(const f32x4*)&R[w * 4352 + (qs2 * 4 + ds) * 256 + lane * 4];
                    float4 o = {a[0] * rinv, a[1] * rinv, a[2] * rinv, a[3] * rinv};
                    *(float4*)&out[((size_t)b * SEQ + qq) * HID + h * HD + ds * 16 + hi * 4] = o;
                }
            }
        }
        __builtin_amdgcn_s_barrier();
    }
}

// ---------------- launcher ----------------
extern "C" void kernel_launch(void* const* d_in, const int* in_sizes, int n_in,
                              void* d_out, int out_size, void* d_ws, size_t ws_size,
                              hipStream_t stream) {
    const float* xq = (const float*)d_in[0];
    const float* xk = (const float*)d_in[1];
    const float* mask = (const float*)d_in[2];
    const float* Wq = (const float*)d_in[3];
    const float* bq = (const float*)d_in[4];
    const float* Wk = (const float*)d_in[5];
    const float* bk = (const float*)d_in[6];
    const float* Wv = (const float*)d_in[7];
    const float* bv = (const float*)d_in[8];
    float* out = (float*)d_out;

    const size_t NX = (size_t)NTOK * HID;      // 4,194,304
    const size_t NW = (size_t)HID * HID;       // 1,048,576
    const size_t need = (5 * NX + 3 * NW) * sizeof(unsigned short) + 2048 * sizeof(int);
    if (ws_size < need) return;

    unsigned short* ws = (unsigned short*)d_ws;
    unsigned short* xq_b = ws;
    unsigned short* xk_b = xq_b + NX;
    unsigned short* wq_b = xk_b + NX;
    unsigned short* wk_b = wq_b + NW;
    unsigned short* wv_b = wk_b + NW;
    unsigned short* Qh = wv_b + NW;
    unsigned short* Kh = Qh + NX;
    unsigned short* Vt = Kh + NX;
    int* flags = (int*)(Vt + NX);

    hipMemsetAsync(flags, 0xFF, 2048 * sizeof(int), stream);
    cvt_all<<<19456, 256, 0, stream>>>(xq, xk, Wq, Wk, Wv, mask,
                                       xq_b, xk_b, wq_b, wk_b, wv_b, flags);
    proj_gemm<<<768, 256, 0, stream>>>(xq_b, xk_b, wq_b, wk_b, wv_b,
                                       bq, bk, bv, Qh, Kh, Vt);
    flash_attn<<<512, 256, 0, stream>>>(Qh, Kh, Vt, mask, flags, out);
}

// Round 16
// 128.404 us; speedup vs baseline: 2.1173x; 2.1173x over previous
//
#include <hip/hip_runtime.h>
#include <hip/hip_bf16.h>

#define HID 1024
#define NH 16
#define HD 64
#define SEQ 2048
#define NB 2
#define NTOK (NB * SEQ)  // 4096

typedef __attribute__((ext_vector_type(8))) short bf16x8;
typedef __attribute__((ext_vector_type(4))) float f32x4;
typedef __attribute__((ext_vector_type(4))) unsigned u32x4;

// softmax runs in log2 domain (native v_exp_f32 = 2^x)
#define QSCALE 0.18033688011112042f   // 0.125 * log2(e)
#define MASKSCALE 1.4426950408889634f

#define MFMA16(a, b, c) __builtin_amdgcn_mfma_f32_16x16x32_bf16((a), (b), (c), 0, 0, 0)

__device__ __forceinline__ unsigned short f2bf(float f) {
    unsigned u = __builtin_bit_cast(unsigned, f);
    u += 0x7FFFu + ((u >> 16) & 1u);   // RNE
    return (unsigned short)(u >> 16);
}
__device__ __forceinline__ unsigned cvtpk(float a, float b) {
    unsigned r;
    asm("v_cvt_pk_bf16_f32 %0, %1, %2" : "=v"(r) : "v"(a), "v"(b));
    return r;
}
__device__ __forceinline__ void gload_lds16(const unsigned short* g, unsigned short* l) {
    __builtin_amdgcn_global_load_lds(
        (const __attribute__((address_space(1))) unsigned int*)g,
        (__attribute__((address_space(3))) unsigned int*)l, 16, 0, 0);
}

// ---------------- merged conversion + flags kernel (6 jobs, one launch) ----------------
__global__ __launch_bounds__(256) void cvt_all(
    const float* __restrict__ xq, const float* __restrict__ xk,
    const float* __restrict__ Wq, const float* __restrict__ Wk, const float* __restrict__ Wv,
    const float* __restrict__ mask,
    unsigned short* __restrict__ dxq, unsigned short* __restrict__ dxk,
    unsigned short* __restrict__ dwq, unsigned short* __restrict__ dwk,
    unsigned short* __restrict__ dwv, int* __restrict__ flags) {
    const int id = blockIdx.x;
    if (id >= 11264) {   // mask -> per-64x64-tile all-ones flags
        const int lane = threadIdx.x & 63;
        int i = ((id - 11264) * 256 + threadIdx.x) * 4;
        float4 v = *(const float4*)(mask + i);
        bool ok = (v.x == 1.0f) && (v.y == 1.0f) && (v.z == 1.0f) && (v.w == 1.0f);
        unsigned long long bal = __ballot(ok);
        int g = lane >> 4;     // each 16-lane group covers 64 contiguous k = one k-tile
        if ((lane & 15) == 0) {
            unsigned m16 = (unsigned)(bal >> (g * 16)) & 0xFFFFu;
            if (m16 != 0xFFFFu) {
                int b = i >> 22;               // SEQ*SEQ = 2^22
                int rem = i & 4194303;
                int q = rem >> 11, k = rem & 2047;
                atomicAnd(&flags[(b << 10) + ((q >> 6) << 5) + (k >> 6)], 0);
            }
        }
        return;
    }
    const float* src;
    unsigned short* dst;
    int base;
    float scale = 1.0f;
    if (id < 4096)       { src = xq; dst = dxq; base = 0; }
    else if (id < 8192)  { src = xk; dst = dxk; base = 4096; }
    else if (id < 9216)  { src = Wq; dst = dwq; base = 8192; scale = QSCALE; }
    else if (id < 10240) { src = Wk; dst = dwk; base = 9216; }
    else                 { src = Wv; dst = dwv; base = 10240; }
    int i = ((id - base) * 256 + threadIdx.x) * 4;
    float4 v = *(const float4*)(src + i);
    ushort4 o;
    o.x = f2bf(v.x * scale); o.y = f2bf(v.y * scale);
    o.z = f2bf(v.z * scale); o.w = f2bf(v.w * scale);
    *(ushort4*)(dst + i) = o;
}

// ---------------- QKV projection GEMMs ----------------
// 768 blocks (flat XCD-swizzled), 128x128 tile, 4 waves, BK=32. A staged via
// 3-buffer LDS ring (counted vmcnt + raw s_barrier); B (the weight/xk panel)
// read DIRECTLY from global — L2-resident 256KB panel, reused across M-blocks.
// Halves DS traffic (proj's measured wall) and halves LDS (24 KB -> more TLP).
// B-loads are issued BEFORE the A-prefetch so the compiler's in-order
// wait-for-bfr doesn't drain stage(t+2).
__global__ __launch_bounds__(256, 4) void proj_gemm(
    const unsigned short* __restrict__ xq, const unsigned short* __restrict__ xk,
    const unsigned short* __restrict__ wq, const unsigned short* __restrict__ wk,
    const unsigned short* __restrict__ wv,
    const float* __restrict__ bq, const float* __restrict__ bk, const float* __restrict__ bv,
    unsigned short* __restrict__ Qh, unsigned short* __restrict__ Kh,
    unsigned short* __restrict__ Vt) {
    __shared__ __align__(16) unsigned short As[3][128 * 32];   // 24 KB total

    const int id = blockIdx.x;
    const int xid = (id & 7) * 96 + (id >> 3);   // 768 = 8*96, bijective XCD swizzle
    const unsigned short *A, *B;
    const float* bias;
    float bsc = 1.0f;
    unsigned short* out;
    int mt, nt;
    bool tr = false;
    if (xid < 256)      { A = xq; B = wq; bias = bq; bsc = QSCALE; out = Qh;
                          mt = xid >> 3; nt = xid & 7; }
    else if (xid < 512) { A = xk; B = wk; bias = bk; out = Kh;
                          mt = (xid - 256) >> 3; nt = (xid - 256) & 7; }
    else                { A = wv; B = xk; bias = bv; out = Vt; tr = true;
                          mt = (xid - 512) & 7; nt = (xid - 512) >> 3; }
    const int m0 = mt * 128, n0 = nt * 128;
    const int tid = threadIdx.x, wave = tid >> 6, lane = tid & 63;
    const int wr = (wave >> 1) * 64, wc = (wave & 1) * 64;
    const int fr = lane & 15, hi = lane >> 4;

    const int uswz = (hi ^ ((fr >> 1) & 3)) << 3;
    const int abase = (wr + fr) * 32 + uswz;

    const int srow = wave * 16 + (lane >> 2);
    const int sunit = (lane & 3) ^ ((lane >> 3) & 3);
    const unsigned short* Asrc = A + (size_t)(m0 + srow) * HID + sunit * 8;
    // B-frag global bases: row n0+wc+j*16+fr, cols t*32 + hi*8
    const unsigned short* Bb = B + (size_t)(n0 + wc + fr) * HID + hi * 8;

    unsigned short *cA = As[0], *nA = As[1], *fA = As[2];

    f32x4 acc[4][4] = {};

#define PSTG(t, ap)                                                              \
    do {                                                                         \
        gload_lds16(Asrc + (t) * 32, (ap) + wave * 512);                         \
        gload_lds16(Asrc + (size_t)64 * HID + (t) * 32, (ap) + 2048 + wave * 512); \
    } while (0)

    PSTG(0, cA);
    PSTG(1, nA);

    for (int t = 0; t < 32; ++t) {
        if (t < 31) asm volatile("s_waitcnt vmcnt(2)" ::: "memory");  // stage(t) done
        else        asm volatile("s_waitcnt vmcnt(0)" ::: "memory");
        __builtin_amdgcn_s_barrier();      // everyone's stage(t) landed; buf(t-1) free

        // B-frags from global FIRST (older than the A-prefetch below)
        bf16x8 bfr[4];
#pragma unroll
        for (int j = 0; j < 4; ++j)
            bfr[j] = *(const bf16x8*)&Bb[(size_t)(j * 16) * HID + t * 32];

        if (t < 30) PSTG(t + 2, fA);       // into the buffer read at t-1

        bf16x8 af[4];
#pragma unroll
        for (int i = 0; i < 4; ++i) af[i] = *(const bf16x8*)&cA[abase + i * 512];
        __builtin_amdgcn_s_setprio(1);
#pragma unroll
        for (int i = 0; i < 4; ++i)
#pragma unroll
            for (int j = 0; j < 4; ++j)
                acc[i][j] = MFMA16(af[i], bfr[j], acc[i][j]);
        __builtin_amdgcn_s_setprio(0);

        unsigned short* ta = cA; cA = nA; nA = fA; fA = ta;
    }
#undef PSTG

#pragma unroll
    for (int i = 0; i < 4; ++i)
#pragma unroll
        for (int j = 0; j < 4; ++j)
#pragma unroll
            for (int r = 0; r < 4; ++r) {
                int row = m0 + wr + i * 16 + hi * 4 + r;   // C/D: row=(lane>>4)*4+reg
                int col = n0 + wc + j * 16 + fr;           //      col=lane&15
                float v = acc[i][j][r];
                if (!tr) {
                    v += bsc * bias[col];
                    int b = row >> 11, l = row & 2047, hh = col >> 6, d = col & 63;
                    out[(((size_t)(b * NH + hh)) * SEQ + l) * HD + d] = f2bf(v);
                } else {
                    v += bias[row];
                    int b = col >> 11, ll = col & 2047, hh = row >> 6, d = row & 63;
                    // sigma: slot-permute k within each 64-block so flash's PV B-frags
                    // are the lane-local cvtpk outputs
                    int lp = (ll & ~0x1C) | ((ll & 0x0C) << 1) | ((ll & 0x10) >> 2);
                    out[(((size_t)(b * NH + hh)) * HD + d) * SEQ + lp] = f2bf(v);
                }
            }
}

// ---------------- flash attention (R10-proven, verbatim) ----------------
// grid 512 (XCD-clustered bh), 4 waves x 32 q (dual Q-group). 4-buffer K/V ring,
// ONE barrier per 2 tiles. No-max log2-domain softmax; PV B-frags direct from
// cvtpk (V slot-permuted at proj); l-sums via ones-MFMA. LDS 64KB = 2 blocks/CU.
__global__ __launch_bounds__(256, 2) void flash_attn(
    const unsigned short* __restrict__ Qh, const unsigned short* __restrict__ Kh,
    const unsigned short* __restrict__ Vt, const float* __restrict__ mask,
    const int* __restrict__ flags, float* __restrict__ out) {
    __shared__ __align__(16) unsigned short Ks[4][64 * 64];   // 32 KB, unit^=(row&7)
    __shared__ __align__(16) unsigned short Vs[4][64 * 64];   // 32 KB, same swizzle

    const int tid = threadIdx.x, wave = tid >> 6, lane = tid & 63;
    const int id = blockIdx.x;                       // 0..511
    const int bh = (id & 7) * 4 + ((id >> 3) & 3);   // XCD-clustered
    const int qi = id >> 5;                          // 128-q tile index 0..15
    const int b = bh >> 4, h = bh & 15;
    const size_t hoff = (size_t)bh * SEQ * HD;
    const int fr = lane & 15, hi = lane >> 4;
    const int f7 = fr & 7, swz3 = f7 << 3;
    const int qa = qi * 128 + wave * 32 + fr;
    const int qb = qa + 16;

    // Q B-frags for both groups (col = q = lane&15, contraction d = hi*8..)
    bf16x8 qfa0 = *(const bf16x8*)&Qh[hoff + (size_t)qa * HD + hi * 8];
    bf16x8 qfa1 = *(const bf16x8*)&Qh[hoff + (size_t)qa * HD + 32 + hi * 8];
    bf16x8 qfb0 = *(const bf16x8*)&Qh[hoff + (size_t)qb * HD + hi * 8];
    bf16x8 qfb1 = *(const bf16x8*)&Qh[hoff + (size_t)qb * HD + 32 + hi * 8];

    const float* mrowA = mask + (size_t)b * SEQ * SEQ + (size_t)qa * SEQ;
    const float* mrowB = mask + (size_t)b * SEQ * SEQ + (size_t)qb * SEQ;
    // this wave's 64-q tile = qi*2 + (wave>>1)
    const int* frow = flags + (b << 10) + ((qi * 2 + (wave >> 1)) << 5);
    int fv = frow[lane & 31];
    const unsigned long long bm = __ballot(fv != 0);   // bit t: tile t all-ones

    // staging: linear LDS dest, inverse-swizzled global source
    const int srow = wave * 8 + (lane >> 3);
    const int sch = (lane & 7) ^ (srow & 7);
    const unsigned short* kbase = Kh + hoff + (size_t)srow * HD + (sch << 3);
    const unsigned short* vbase = Vt + hoff + (size_t)srow * SEQ + (sch << 3);

    f32x4 accA[4] = {}, accB[4] = {};
    f32x4 laccA = {}, laccB = {};
    const bf16x8 ones = {0x3F80, 0x3F80, 0x3F80, 0x3F80, 0x3F80, 0x3F80, 0x3F80, 0x3F80};

#define STG(t, kd, vd)                                                           \
    do {                                                                         \
        gload_lds16(kbase + (size_t)(t) * 64 * HD, (kd) + (wave * 8) * 64);      \
        gload_lds16(kbase + (size_t)((t) * 64 + 32) * HD, (kd) + (wave * 8 + 32) * 64); \
        gload_lds16(vbase + (t) * 64, (vd) + (wave * 8) * 64);                   \
        gload_lds16(vbase + (size_t)32 * SEQ + (t) * 64, (vd) + (wave * 8 + 32) * 64); \
    } while (0)

#define FTILE(kd, vd, tt)                                                        \
    do {                                                                         \
        f32x4 sA[4], sB[4];                                                      \
        __builtin_amdgcn_s_setprio(1);                                           \
        _Pragma("unroll")                                                        \
        for (int sub = 0; sub < 4; ++sub) {                                      \
            const int rbase = (sub * 16 + fr) * 64;                              \
            bf16x8 kf0 = *(const bf16x8*)&(kd)[rbase + ((hi << 3) ^ swz3)];      \
            bf16x8 kf1 = *(const bf16x8*)&(kd)[rbase + (((hi + 4) << 3) ^ swz3)]; \
            f32x4 z = {0.f, 0.f, 0.f, 0.f};                                      \
            z = MFMA16(kf0, qfa0, z);                                            \
            z = MFMA16(kf1, qfa1, z);                                            \
            sA[sub] = z;                                                         \
            f32x4 w = {0.f, 0.f, 0.f, 0.f};                                      \
            w = MFMA16(kf0, qfb0, w);                                            \
            w = MFMA16(kf1, qfb1, w);                                            \
            sB[sub] = w;                                                         \
        }                                                                        \
        __builtin_amdgcn_s_setprio(0);                                           \
        if (!((bm >> (tt)) & 1)) {   /* raw f32 fallback (never taken here) */   \
            const int k0 = (tt) * 64;                                            \
            _Pragma("unroll")                                                    \
            for (int sub = 0; sub < 4; ++sub) {                                  \
                float4 ma = *(const float4*)&mrowA[k0 + sub * 16 + hi * 4];      \
                sA[sub][0] += (1.f - ma.x) * (-10000.f * MASKSCALE);             \
                sA[sub][1] += (1.f - ma.y) * (-10000.f * MASKSCALE);             \
                sA[sub][2] += (1.f - ma.z) * (-10000.f * MASKSCALE);             \
                sA[sub][3] += (1.f - ma.w) * (-10000.f * MASKSCALE);             \
                float4 mv = *(const float4*)&mrowB[k0 + sub * 16 + hi * 4];      \
                sB[sub][0] += (1.f - mv.x) * (-10000.f * MASKSCALE);             \
                sB[sub][1] += (1.f - mv.y) * (-10000.f * MASKSCALE);             \
                sB[sub][2] += (1.f - mv.z) * (-10000.f * MASKSCALE);             \
                sB[sub][3] += (1.f - mv.w) * (-10000.f * MASKSCALE);             \
            }                                                                    \
        }                                                                        \
        _Pragma("unroll")                                                        \
        for (int sub = 0; sub < 4; ++sub)                                        \
            _Pragma("unroll")                                                    \
            for (int r = 0; r < 4; ++r) {                                        \
                sA[sub][r] = __builtin_amdgcn_exp2f(sA[sub][r]);                 \
                sB[sub][r] = __builtin_amdgcn_exp2f(sB[sub][r]);                 \
            }                                                                    \
        u32x4 wa0, wa1, wb0, wb1;                                                \
        wa0[0] = cvtpk(sA[0][0], sA[0][1]); wa0[1] = cvtpk(sA[0][2], sA[0][3]);  \
        wa0[2] = cvtpk(sA[1][0], sA[1][1]); wa0[3] = cvtpk(sA[1][2], sA[1][3]);  \
        wa1[0] = cvtpk(sA[2][0], sA[2][1]); wa1[1] = cvtpk(sA[2][2], sA[2][3]);  \
        wa1[2] = cvtpk(sA[3][0], sA[3][1]); wa1[3] = cvtpk(sA[3][2], sA[3][3]);  \
        wb0[0] = cvtpk(sB[0][0], sB[0][1]); wb0[1] = cvtpk(sB[0][2], sB[0][3]);  \
        wb0[2] = cvtpk(sB[1][0], sB[1][1]); wb0[3] = cvtpk(sB[1][2], sB[1][3]);  \
        wb1[0] = cvtpk(sB[2][0], sB[2][1]); wb1[1] = cvtpk(sB[2][2], sB[2][3]);  \
        wb1[2] = cvtpk(sB[3][0], sB[3][1]); wb1[3] = cvtpk(sB[3][2], sB[3][3]);  \
        bf16x8 pA0 = __builtin_bit_cast(bf16x8, wa0);                            \
        bf16x8 pA1 = __builtin_bit_cast(bf16x8, wa1);                            \
        bf16x8 pB0 = __builtin_bit_cast(bf16x8, wb0);                            \
        bf16x8 pB1 = __builtin_bit_cast(bf16x8, wb1);                            \
        __builtin_amdgcn_s_setprio(1);                                           \
        laccA = MFMA16(ones, pA0, laccA);                                        \
        laccA = MFMA16(ones, pA1, laccA);                                        \
        laccB = MFMA16(ones, pB0, laccB);                                        \
        laccB = MFMA16(ones, pB1, laccB);                                        \
        _Pragma("unroll")                                                        \
        for (int sub = 0; sub < 4; ++sub) {                                      \
            const int rbase = (sub * 16 + fr) * 64;                              \
            bf16x8 vf0 = *(const bf16x8*)&(vd)[rbase + ((hi << 3) ^ swz3)];      \
            bf16x8 vf1 = *(const bf16x8*)&(vd)[rbase + (((hi + 4) << 3) ^ swz3)]; \
            accA[sub] = MFMA16(vf0, pA0, accA[sub]);                             \
            accA[sub] = MFMA16(vf1, pA1, accA[sub]);                             \
            accB[sub] = MFMA16(vf0, pB0, accB[sub]);                             \
            accB[sub] = MFMA16(vf1, pB1, accB[sub]);                             \
        }                                                                        \
        __builtin_amdgcn_s_setprio(0);                                           \
    } while (0)

    STG(0, Ks[0], Vs[0]);
    STG(1, Ks[1], Vs[1]);

    for (int ii = 0; ii < 8; ++ii) {
        const int t0 = ii * 4;
        // even interval: compute bufs 0,1 (tiles t0,t0+1); stage tiles t0+2,t0+3 -> bufs 2,3
        asm volatile("s_waitcnt vmcnt(0)" ::: "memory");   // own stages for t0,t0+1 landed
        __builtin_amdgcn_s_barrier();                      // all landed; bufs 2,3 free
        STG(t0 + 2, Ks[2], Vs[2]);
        STG(t0 + 3, Ks[3], Vs[3]);
        FTILE(Ks[0], Vs[0], t0);
        FTILE(Ks[1], Vs[1], t0 + 1);
        // odd interval: compute bufs 2,3; stage tiles t0+4,t0+5 -> bufs 0,1
        asm volatile("s_waitcnt vmcnt(0)" ::: "memory");
        __builtin_amdgcn_s_barrier();
        if (ii < 7) {
            STG(t0 + 4, Ks[0], Vs[0]);
            STG(t0 + 5, Ks[1], Vs[1]);
        }
        FTILE(Ks[2], Vs[2], t0 + 2);
        FTILE(Ks[3], Vs[3], t0 + 3);
    }
#undef STG
#undef FTILE

    // epilogue
    float rA = 1.0f / laccA[0], rB = 1.0f / laccB[0];
#pragma unroll
    for (int sub = 0; sub < 4; ++sub) {
        float4 oA = {accA[sub][0] * rA, accA[sub][1] * rA, accA[sub][2] * rA, accA[sub][3] * rA};
        *(float4*)&out[((size_t)b * SEQ + qa) * HID + h * HD + sub * 16 + hi * 4] = oA;
        float4 oB = {accB[sub][0] * rB, accB[sub][1] * rB, accB[sub][2] * rB, accB[sub][3] * rB};
        *(float4*)&out[((size_t)b * SEQ + qb) * HID + h * HD + sub * 16 + hi * 4] = oB;
    }
}

// ---------------- launcher ----------------
extern "C" void kernel_launch(void* const* d_in, const int* in_sizes, int n_in,
                              void* d_out, int out_size, void* d_ws, size_t ws_size,
                              hipStream_t stream) {
    const float* xq = (const float*)d_in[0];
    const float* xk = (const float*)d_in[1];
    const float* mask = (const float*)d_in[2];
    const float* Wq = (const float*)d_in[3];
    const float* bq = (const float*)d_in[4];
    const float* Wk = (const float*)d_in[5];
    const float* bk = (const float*)d_in[6];
    const float* Wv = (const float*)d_in[7];
    const float* bv = (const float*)d_in[8];
    float* out = (float*)d_out;

    const size_t NX = (size_t)NTOK * HID;      // 4,194,304
    const size_t NW = (size_t)HID * HID;       // 1,048,576
    const size_t need = (5 * NX + 3 * NW) * sizeof(unsigned short) + 2048 * sizeof(int);
    if (ws_size < need) return;

    unsigned short* ws = (unsigned short*)d_ws;
    unsigned short* xq_b = ws;
    unsigned short* xk_b = xq_b + NX;
    unsigned short* wq_b = xk_b + NX;
    unsigned short* wk_b = wq_b + NW;
    unsigned short* wv_b = wk_b + NW;
    unsigned short* Qh = wv_b + NW;
    unsigned short* Kh = Qh + NX;
    unsigned short* Vt = Kh + NX;
    int* flags = (int*)(Vt + NX);

    hipMemsetAsync(flags, 0xFF, 2048 * sizeof(int), stream);
    cvt_all<<<19456, 256, 0, stream>>>(xq, xk, Wq, Wk, Wv, mask,
                                       xq_b, xk_b, wq_b, wk_b, wv_b, flags);
    proj_gemm<<<768, 256, 0, stream>>>(xq_b, xk_b, wq_b, wk_b, wv_b,
                                       bq, bk, bv, Qh, Kh, Vt);
    flash_attn<<<512, 256, 0, stream>>>(Qh, Kh, Vt, mask, flags, out);
}

// Round 17
// 115.467 us; speedup vs baseline: 2.3546x; 1.1120x over previous
//
#include <hip/hip_runtime.h>
#include <hip/hip_bf16.h>

#define HID 1024
#define NH 16
#define HD 64
#define SEQ 2048
#define NB 2
#define NTOK (NB * SEQ)  // 4096

typedef __attribute__((ext_vector_type(8))) short bf16x8;
typedef __attribute__((ext_vector_type(4))) float f32x4;
typedef __attribute__((ext_vector_type(4))) unsigned u32x4;

// softmax runs in log2 domain (native v_exp_f32 = 2^x)
#define QSCALE 0.18033688011112042f   // 0.125 * log2(e)
#define MASKSCALE 1.4426950408889634f

#define MFMA16(a, b, c) __builtin_amdgcn_mfma_f32_16x16x32_bf16((a), (b), (c), 0, 0, 0)

__device__ __forceinline__ unsigned short f2bf(float f) {
    unsigned u = __builtin_bit_cast(unsigned, f);
    u += 0x7FFFu + ((u >> 16) & 1u);   // RNE
    return (unsigned short)(u >> 16);
}
__device__ __forceinline__ unsigned cvtpk(float a, float b) {
    unsigned r;
    asm("v_cvt_pk_bf16_f32 %0, %1, %2" : "=v"(r) : "v"(a), "v"(b));
    return r;
}
__device__ __forceinline__ void gload_lds16(const unsigned short* g, unsigned short* l) {
    __builtin_amdgcn_global_load_lds(
        (const __attribute__((address_space(1))) unsigned int*)g,
        (__attribute__((address_space(3))) unsigned int*)l, 16, 0, 0);
}

// ---------------- merged conversion + flags kernel (6 jobs, one launch) ----------------
__global__ __launch_bounds__(256) void cvt_all(
    const float* __restrict__ xq, const float* __restrict__ xk,
    const float* __restrict__ Wq, const float* __restrict__ Wk, const float* __restrict__ Wv,
    const float* __restrict__ mask,
    unsigned short* __restrict__ dxq, unsigned short* __restrict__ dxk,
    unsigned short* __restrict__ dwq, unsigned short* __restrict__ dwk,
    unsigned short* __restrict__ dwv, int* __restrict__ flags) {
    const int id = blockIdx.x;
    if (id >= 11264) {   // mask -> per-64x64-tile all-ones flags
        const int lane = threadIdx.x & 63;
        int i = ((id - 11264) * 256 + threadIdx.x) * 4;
        float4 v = *(const float4*)(mask + i);
        bool ok = (v.x == 1.0f) && (v.y == 1.0f) && (v.z == 1.0f) && (v.w == 1.0f);
        unsigned long long bal = __ballot(ok);
        int g = lane >> 4;     // each 16-lane group covers 64 contiguous k = one k-tile
        if ((lane & 15) == 0) {
            unsigned m16 = (unsigned)(bal >> (g * 16)) & 0xFFFFu;
            if (m16 != 0xFFFFu) {
                int b = i >> 22;               // SEQ*SEQ = 2^22
                int rem = i & 4194303;
                int q = rem >> 11, k = rem & 2047;
                atomicAnd(&flags[(b << 10) + ((q >> 6) << 5) + (k >> 6)], 0);
            }
        }
        return;
    }
    const float* src;
    unsigned short* dst;
    int base;
    float scale = 1.0f;
    if (id < 4096)       { src = xq; dst = dxq; base = 0; }
    else if (id < 8192)  { src = xk; dst = dxk; base = 4096; }
    else if (id < 9216)  { src = Wq; dst = dwq; base = 8192; scale = QSCALE; }
    else if (id < 10240) { src = Wk; dst = dwk; base = 9216; }
    else                 { src = Wv; dst = dwv; base = 10240; }
    int i = ((id - base) * 256 + threadIdx.x) * 4;
    float4 v = *(const float4*)(src + i);
    ushort4 o;
    o.x = f2bf(v.x * scale); o.y = f2bf(v.y * scale);
    o.z = f2bf(v.z * scale); o.w = f2bf(v.w * scale);
    *(ushort4*)(dst + i) = o;
}

// ---------------- QKV projection GEMMs ----------------
// 768 blocks (flat XCD-swizzled), 128x128 tile, 4 waves, BK=32. 4-buffer ring
// with ONE vmcnt(0)+s_barrier per 2 K-steps (flash-R10 pairing transplant):
// 32 MFMA + 16 ds_reads of ILP between syncs, stages get a full interval of
// cover. LDS 64KB = 2 blocks/CU. XOR-swizzled LDS (unit^=(row>>1)&3).
__global__ __launch_bounds__(256, 2) void proj_gemm(
    const unsigned short* __restrict__ xq, const unsigned short* __restrict__ xk,
    const unsigned short* __restrict__ wq, const unsigned short* __restrict__ wk,
    const unsigned short* __restrict__ wv,
    const float* __restrict__ bq, const float* __restrict__ bk, const float* __restrict__ bv,
    unsigned short* __restrict__ Qh, unsigned short* __restrict__ Kh,
    unsigned short* __restrict__ Vt) {
    __shared__ __align__(16) unsigned short As[4][128 * 32];   // 32 KB
    __shared__ __align__(16) unsigned short Bs[4][128 * 32];   // 32 KB

    const int id = blockIdx.x;
    const int xid = (id & 7) * 96 + (id >> 3);   // 768 = 8*96, bijective XCD swizzle
    const unsigned short *A, *B;
    const float* bias;
    float bsc = 1.0f;
    unsigned short* out;
    int mt, nt;
    bool tr = false;
    if (xid < 256)      { A = xq; B = wq; bias = bq; bsc = QSCALE; out = Qh;
                          mt = xid >> 3; nt = xid & 7; }
    else if (xid < 512) { A = xk; B = wk; bias = bk; out = Kh;
                          mt = (xid - 256) >> 3; nt = (xid - 256) & 7; }
    else                { A = wv; B = xk; bias = bv; out = Vt; tr = true;
                          mt = (xid - 512) & 7; nt = (xid - 512) >> 3; }
    const int m0 = mt * 128, n0 = nt * 128;
    const int tid = threadIdx.x, wave = tid >> 6, lane = tid & 63;
    const int wr = (wave >> 1) * 64, wc = (wave & 1) * 64;
    const int fr = lane & 15, hi = lane >> 4;

    const int uswz = (hi ^ ((fr >> 1) & 3)) << 3;
    const int abase = (wr + fr) * 32 + uswz;
    const int bbase = (wc + fr) * 32 + uswz;

    const int srow = wave * 16 + (lane >> 2);
    const int sunit = (lane & 3) ^ ((lane >> 3) & 3);
    const unsigned short* Asrc = A + (size_t)(m0 + srow) * HID + sunit * 8;
    const unsigned short* Bsrc = B + (size_t)(n0 + srow) * HID + sunit * 8;

    f32x4 acc[4][4] = {};

#define PSTG(t, ap, bp)                                                          \
    do {                                                                         \
        gload_lds16(Asrc + (t) * 32, (ap) + wave * 512);                         \
        gload_lds16(Asrc + (size_t)64 * HID + (t) * 32, (ap) + 2048 + wave * 512); \
        gload_lds16(Bsrc + (t) * 32, (bp) + wave * 512);                         \
        gload_lds16(Bsrc + (size_t)64 * HID + (t) * 32, (bp) + 2048 + wave * 512); \
    } while (0)

#define CSTEP(ap, bp)                                                            \
    do {                                                                         \
        bf16x8 af[4], bfr[4];                                                    \
        _Pragma("unroll")                                                        \
        for (int i = 0; i < 4; ++i) af[i] = *(const bf16x8*)&(ap)[abase + i * 512]; \
        _Pragma("unroll")                                                        \
        for (int j = 0; j < 4; ++j) bfr[j] = *(const bf16x8*)&(bp)[bbase + j * 512]; \
        __builtin_amdgcn_s_setprio(1);                                           \
        _Pragma("unroll")                                                        \
        for (int i = 0; i < 4; ++i)                                              \
            _Pragma("unroll")                                                    \
            for (int j = 0; j < 4; ++j)                                          \
                acc[i][j] = MFMA16(af[i], bfr[j], acc[i][j]);                    \
        __builtin_amdgcn_s_setprio(0);                                           \
    } while (0)

    PSTG(0, As[0], Bs[0]);
    PSTG(1, As[1], Bs[1]);

    for (int ii = 0; ii < 8; ++ii) {
        const int t0 = ii * 4;
        // even interval: compute steps t0,t0+1 (bufs 0,1); stage t0+2,t0+3 -> bufs 2,3
        asm volatile("s_waitcnt vmcnt(0)" ::: "memory");   // stages for bufs 0,1 landed
        __builtin_amdgcn_s_barrier();                      // all landed; bufs 2,3 retired
        PSTG(t0 + 2, As[2], Bs[2]);
        PSTG(t0 + 3, As[3], Bs[3]);
        CSTEP(As[0], Bs[0]);
        CSTEP(As[1], Bs[1]);
        // odd interval: compute bufs 2,3; stage t0+4,t0+5 -> bufs 0,1
        asm volatile("s_waitcnt vmcnt(0)" ::: "memory");
        __builtin_amdgcn_s_barrier();
        if (ii < 7) {
            PSTG(t0 + 4, As[0], Bs[0]);
            PSTG(t0 + 5, As[1], Bs[1]);
        }
        CSTEP(As[2], Bs[2]);
        CSTEP(As[3], Bs[3]);
    }
#undef PSTG
#undef CSTEP

#pragma unroll
    for (int i = 0; i < 4; ++i)
#pragma unroll
        for (int j = 0; j < 4; ++j)
#pragma unroll
            for (int r = 0; r < 4; ++r) {
                int row = m0 + wr + i * 16 + hi * 4 + r;   // C/D: row=(lane>>4)*4+reg
                int col = n0 + wc + j * 16 + fr;           //      col=lane&15
                float v = acc[i][j][r];
                if (!tr) {
                    v += bsc * bias[col];
                    int b = row >> 11, l = row & 2047, hh = col >> 6, d = col & 63;
                    out[(((size_t)(b * NH + hh)) * SEQ + l) * HD + d] = f2bf(v);
                } else {
                    v += bias[row];
                    int b = col >> 11, ll = col & 2047, hh = row >> 6, d = row & 63;
                    // sigma: slot-permute k within each 64-block so flash's PV B-frags
                    // are the lane-local cvtpk outputs
                    int lp = (ll & ~0x1C) | ((ll & 0x0C) << 1) | ((ll & 0x10) >> 2);
                    out[(((size_t)(b * NH + hh)) * HD + d) * SEQ + lp] = f2bf(v);
                }
            }
}

// ---------------- flash attention (R10-proven, verbatim) ----------------
// grid 512 (XCD-clustered bh), 4 waves x 32 q (dual Q-group). 4-buffer K/V ring,
// ONE barrier per 2 tiles. No-max log2-domain softmax; PV B-frags direct from
// cvtpk (V slot-permuted at proj); l-sums via ones-MFMA. LDS 64KB = 2 blocks/CU.
__global__ __launch_bounds__(256, 2) void flash_attn(
    const unsigned short* __restrict__ Qh, const unsigned short* __restrict__ Kh,
    const unsigned short* __restrict__ Vt, const float* __restrict__ mask,
    const int* __restrict__ flags, float* __restrict__ out) {
    __shared__ __align__(16) unsigned short Ks[4][64 * 64];   // 32 KB, unit^=(row&7)
    __shared__ __align__(16) unsigned short Vs[4][64 * 64];   // 32 KB, same swizzle

    const int tid = threadIdx.x, wave = tid >> 6, lane = tid & 63;
    const int id = blockIdx.x;                       // 0..511
    const int bh = (id & 7) * 4 + ((id >> 3) & 3);   // XCD-clustered
    const int qi = id >> 5;                          // 128-q tile index 0..15
    const int b = bh >> 4, h = bh & 15;
    const size_t hoff = (size_t)bh * SEQ * HD;
    const int fr = lane & 15, hi = lane >> 4;
    const int f7 = fr & 7, swz3 = f7 << 3;
    const int qa = qi * 128 + wave * 32 + fr;
    const int qb = qa + 16;

    // Q B-frags for both groups (col = q = lane&15, contraction d = hi*8..)
    bf16x8 qfa0 = *(const bf16x8*)&Qh[hoff + (size_t)qa * HD + hi * 8];
    bf16x8 qfa1 = *(const bf16x8*)&Qh[hoff + (size_t)qa * HD + 32 + hi * 8];
    bf16x8 qfb0 = *(const bf16x8*)&Qh[hoff + (size_t)qb * HD + hi * 8];
    bf16x8 qfb1 = *(const bf16x8*)&Qh[hoff + (size_t)qb * HD + 32 + hi * 8];

    const float* mrowA = mask + (size_t)b * SEQ * SEQ + (size_t)qa * SEQ;
    const float* mrowB = mask + (size_t)b * SEQ * SEQ + (size_t)qb * SEQ;
    // this wave's 64-q tile = qi*2 + (wave>>1)
    const int* frow = flags + (b << 10) + ((qi * 2 + (wave >> 1)) << 5);
    int fv = frow[lane & 31];
    const unsigned long long bm = __ballot(fv != 0);   // bit t: tile t all-ones

    // staging: linear LDS dest, inverse-swizzled global source
    const int srow = wave * 8 + (lane >> 3);
    const int sch = (lane & 7) ^ (srow & 7);
    const unsigned short* kbase = Kh + hoff + (size_t)srow * HD + (sch << 3);
    const unsigned short* vbase = Vt + hoff + (size_t)srow * SEQ + (sch << 3);

    f32x4 accA[4] = {}, accB[4] = {};
    f32x4 laccA = {}, laccB = {};
    const bf16x8 ones = {0x3F80, 0x3F80, 0x3F80, 0x3F80, 0x3F80, 0x3F80, 0x3F80, 0x3F80};

#define STG(t, kd, vd)                                                           \
    do {                                                                         \
        gload_lds16(kbase + (size_t)(t) * 64 * HD, (kd) + (wave * 8) * 64);      \
        gload_lds16(kbase + (size_t)((t) * 64 + 32) * HD, (kd) + (wave * 8 + 32) * 64); \
        gload_lds16(vbase + (t) * 64, (vd) + (wave * 8) * 64);                   \
        gload_lds16(vbase + (size_t)32 * SEQ + (t) * 64, (vd) + (wave * 8 + 32) * 64); \
    } while (0)

#define FTILE(kd, vd, tt)                                                        \
    do {                                                                         \
        f32x4 sA[4], sB[4];                                                      \
        __builtin_amdgcn_s_setprio(1);                                           \
        _Pragma("unroll")                                                        \
        for (int sub = 0; sub < 4; ++sub) {                                      \
            const int rbase = (sub * 16 + fr) * 64;                              \
            bf16x8 kf0 = *(const bf16x8*)&(kd)[rbase + ((hi << 3) ^ swz3)];      \
            bf16x8 kf1 = *(const bf16x8*)&(kd)[rbase + (((hi + 4) << 3) ^ swz3)]; \
            f32x4 z = {0.f, 0.f, 0.f, 0.f};                                      \
            z = MFMA16(kf0, qfa0, z);                                            \
            z = MFMA16(kf1, qfa1, z);                                            \
            sA[sub] = z;                                                         \
            f32x4 w = {0.f, 0.f, 0.f, 0.f};                                      \
            w = MFMA16(kf0, qfb0, w);                                            \
            w = MFMA16(kf1, qfb1, w);                                            \
            sB[sub] = w;                                                         \
        }                                                                        \
        __builtin_amdgcn_s_setprio(0);                                           \
        if (!((bm >> (tt)) & 1)) {   /* raw f32 fallback (never taken here) */   \
            const int k0 = (tt) * 64;                                            \
            _Pragma("unroll")                                                    \
            for (int sub = 0; sub < 4; ++sub) {                                  \
                float4 ma = *(const float4*)&mrowA[k0 + sub * 16 + hi * 4];      \
                sA[sub][0] += (1.f - ma.x) * (-10000.f * MASKSCALE);             \
                sA[sub][1] += (1.f - ma.y) * (-10000.f * MASKSCALE);             \
                sA[sub][2] += (1.f - ma.z) * (-10000.f * MASKSCALE);             \
                sA[sub][3] += (1.f - ma.w) * (-10000.f * MASKSCALE);             \
                float4 mv = *(const float4*)&mrowB[k0 + sub * 16 + hi * 4];      \
                sB[sub][0] += (1.f - mv.x) * (-10000.f * MASKSCALE);             \
                sB[sub][1] += (1.f - mv.y) * (-10000.f * MASKSCALE);             \
                sB[sub][2] += (1.f - mv.z) * (-10000.f * MASKSCALE);             \
                sB[sub][3] += (1.f - mv.w) * (-10000.f * MASKSCALE);             \
            }                                                                    \
        }                                                                        \
        _Pragma("unroll")                                                        \
        for (int sub = 0; sub < 4; ++sub)                                        \
            _Pragma("unroll")                                                    \
            for (int r = 0; r < 4; ++r) {                                        \
                sA[sub][r] = __builtin_amdgcn_exp2f(sA[sub][r]);                 \
                sB[sub][r] = __builtin_amdgcn_exp2f(sB[sub][r]);                 \
            }                                                                    \
        u32x4 wa0, wa1, wb0, wb1;                                                \
        wa0[0] = cvtpk(sA[0][0], sA[0][1]); wa0[1] = cvtpk(sA[0][2], sA[0][3]);  \
        wa0[2] = cvtpk(sA[1][0], sA[1][1]); wa0[3] = cvtpk(sA[1][2], sA[1][3]);  \
        wa1[0] = cvtpk(sA[2][0], sA[2][1]); wa1[1] = cvtpk(sA[2][2], sA[2][3]);  \
        wa1[2] = cvtpk(sA[3][0], sA[3][1]); wa1[3] = cvtpk(sA[3][2], sA[3][3]);  \
        wb0[0] = cvtpk(sB[0][0], sB[0][1]); wb0[1] = cvtpk(sB[0][2], sB[0][3]);  \
        wb0[2] = cvtpk(sB[1][0], sB[1][1]); wb0[3] = cvtpk(sB[1][2], sB[1][3]);  \
        wb1[0] = cvtpk(sB[2][0], sB[2][1]); wb1[1] = cvtpk(sB[2][2], sB[2][3]);  \
        wb1[2] = cvtpk(sB[3][0], sB[3][1]); wb1[3] = cvtpk(sB[3][2], sB[3][3]);  \
        bf16x8 pA0 = __builtin_bit_cast(bf16x8, wa0);                            \
        bf16x8 pA1 = __builtin_bit_cast(bf16x8, wa1);                            \
        bf16x8 pB0 = __builtin_bit_cast(bf16x8, wb0);                            \
        bf16x8 pB1 = __builtin_bit_cast(bf16x8, wb1);                            \
        __builtin_amdgcn_s_setprio(1);                                           \
        laccA = MFMA16(ones, pA0, laccA);                                        \
        laccA = MFMA16(ones, pA1, laccA);                                        \
        laccB = MFMA16(ones, pB0, laccB);                                        \
        laccB = MFMA16(ones, pB1, laccB);                                        \
        _Pragma("unroll")                                                        \
        for (int sub = 0; sub < 4; ++sub) {                                      \
            const int rbase = (sub * 16 + fr) * 64;                              \
            bf16x8 vf0 = *(const bf16x8*)&(vd)[rbase + ((hi << 3) ^ swz3)];      \
            bf16x8 vf1 = *(const bf16x8*)&(vd)[rbase + (((hi + 4) << 3) ^ swz3)]; \
            accA[sub] = MFMA16(vf0, pA0, accA[sub]);                             \
            accA[sub] = MFMA16(vf1, pA1, accA[sub]);                             \
            accB[sub] = MFMA16(vf0, pB0, accB[sub]);                             \
            accB[sub] = MFMA16(vf1, pB1, accB[sub]);                             \
        }                                                                        \
        __builtin_amdgcn_s_setprio(0);                                           \
    } while (0)

    STG(0, Ks[0], Vs[0]);
    STG(1, Ks[1], Vs[1]);

    for (int ii = 0; ii < 8; ++ii) {
        const int t0 = ii * 4;
        // even interval: compute bufs 0,1 (tiles t0,t0+1); stage tiles t0+2,t0+3 -> bufs 2,3
        asm volatile("s_waitcnt vmcnt(0)" ::: "memory");   // own stages for t0,t0+1 landed
        __builtin_amdgcn_s_barrier();                      // all landed; bufs 2,3 free
        STG(t0 + 2, Ks[2], Vs[2]);
        STG(t0 + 3, Ks[3], Vs[3]);
        FTILE(Ks[0], Vs[0], t0);
        FTILE(Ks[1], Vs[1], t0 + 1);
        // odd interval: compute bufs 2,3; stage tiles t0+4,t0+5 -> bufs 0,1
        asm volatile("s_waitcnt vmcnt(0)" ::: "memory");
        __builtin_amdgcn_s_barrier();
        if (ii < 7) {
            STG(t0 + 4, Ks[0], Vs[0]);
            STG(t0 + 5, Ks[1], Vs[1]);
        }
        FTILE(Ks[2], Vs[2], t0 + 2);
        FTILE(Ks[3], Vs[3], t0 + 3);
    }
#undef STG
#undef FTILE

    // epilogue
    float rA = 1.0f / laccA[0], rB = 1.0f / laccB[0];
#pragma unroll
    for (int sub = 0; sub < 4; ++sub) {
        float4 oA = {accA[sub][0] * rA, accA[sub][1] * rA, accA[sub][2] * rA, accA[sub][3] * rA};
        *(float4*)&out[((size_t)b * SEQ + qa) * HID + h * HD + sub * 16 + hi * 4] = oA;
        float4 oB = {accB[sub][0] * rB, accB[sub][1] * rB, accB[sub][2] * rB, accB[sub][3] * rB};
        *(float4*)&out[((size_t)b * SEQ + qb) * HID + h * HD + sub * 16 + hi * 4] = oB;
    }
}

// ---------------- launcher ----------------
extern "C" void kernel_launch(void* const* d_in, const int* in_sizes, int n_in,
                              void* d_out, int out_size, void* d_ws, size_t ws_size,
                              hipStream_t stream) {
    const float* xq = (const float*)d_in[0];
    const float* xk = (const float*)d_in[1];
    const float* mask = (const float*)d_in[2];
    const float* Wq = (const float*)d_in[3];
    const float* bq = (const float*)d_in[4];
    const float* Wk = (const float*)d_in[5];
    const float* bk = (const float*)d_in[6];
    const float* Wv = (const float*)d_in[7];
    const float* bv = (const float*)d_in[8];
    float* out = (float*)d_out;

    const size_t NX = (size_t)NTOK * HID;      // 4,194,304
    const size_t NW = (size_t)HID * HID;       // 1,048,576
    const size_t need = (5 * NX + 3 * NW) * sizeof(unsigned short) + 2048 * sizeof(int);
    if (ws_size < need) return;

    unsigned short* ws = (unsigned short*)d_ws;
    unsigned short* xq_b = ws;
    unsigned short* xk_b = xq_b + NX;
    unsigned short* wq_b = xk_b + NX;
    unsigned short* wk_b = wq_b + NW;
    unsigned short* wv_b = wk_b + NW;
    unsigned short* Qh = wv_b + NW;
    unsigned short* Kh = Qh + NX;
    unsigned short* Vt = Kh + NX;
    int* flags = (int*)(Vt + NX);

    hipMemsetAsync(flags, 0xFF, 2048 * sizeof(int), stream);
    cvt_all<<<19456, 256, 0, stream>>>(xq, xk, Wq, Wk, Wv, mask,
                                       xq_b, xk_b, wq_b, wk_b, wv_b, flags);
    proj_gemm<<<768, 256, 0, stream>>>(xq_b, xk_b, wq_b, wk_b, wv_b,
                                       bq, bk, bv, Qh, Kh, Vt);
    flash_attn<<<512, 256, 0, stream>>>(Qh, Kh, Vt, mask, flags, out);
}

// Round 18
// 102.807 us; speedup vs baseline: 2.6445x; 1.1231x over previous
//
#include <hip/hip_runtime.h>
#include <hip/hip_bf16.h>

#define HID 1024
#define NH 16
#define HD 64
#define SEQ 2048
#define NB 2
#define NTOK (NB * SEQ)  // 4096

typedef __attribute__((ext_vector_type(8))) short bf16x8;
typedef __attribute__((ext_vector_type(4))) float f32x4;
typedef __attribute__((ext_vector_type(4))) unsigned u32x4;

// softmax runs in log2 domain (native v_exp_f32 = 2^x)
#define QSCALE 0.18033688011112042f   // 0.125 * log2(e)
#define MASKSCALE 1.4426950408889634f

#define MFMA16(a, b, c) __builtin_amdgcn_mfma_f32_16x16x32_bf16((a), (b), (c), 0, 0, 0)

__device__ __forceinline__ unsigned short f2bf(float f) {
    unsigned u = __builtin_bit_cast(unsigned, f);
    u += 0x7FFFu + ((u >> 16) & 1u);   // RNE
    return (unsigned short)(u >> 16);
}
__device__ __forceinline__ unsigned cvtpk(float a, float b) {
    unsigned r;
    asm("v_cvt_pk_bf16_f32 %0, %1, %2" : "=v"(r) : "v"(a), "v"(b));
    return r;
}
__device__ __forceinline__ void gload_lds16(const unsigned short* g, unsigned short* l) {
    __builtin_amdgcn_global_load_lds(
        (const __attribute__((address_space(1))) unsigned int*)g,
        (__attribute__((address_space(3))) unsigned int*)l, 16, 0, 0);
}

// ---------------- merged conversion + flags kernel (6 jobs, one launch) ----------------
__global__ __launch_bounds__(256) void cvt_all(
    const float* __restrict__ xq, const float* __restrict__ xk,
    const float* __restrict__ Wq, const float* __restrict__ Wk, const float* __restrict__ Wv,
    const float* __restrict__ mask,
    unsigned short* __restrict__ dxq, unsigned short* __restrict__ dxk,
    unsigned short* __restrict__ dwq, unsigned short* __restrict__ dwk,
    unsigned short* __restrict__ dwv, int* __restrict__ flags) {
    const int id = blockIdx.x;
    if (id >= 11264) {   // mask -> per-64x64-tile all-ones flags
        const int lane = threadIdx.x & 63;
        int i = ((id - 11264) * 256 + threadIdx.x) * 4;
        float4 v = *(const float4*)(mask + i);
        bool ok = (v.x == 1.0f) && (v.y == 1.0f) && (v.z == 1.0f) && (v.w == 1.0f);
        unsigned long long bal = __ballot(ok);
        int g = lane >> 4;     // each 16-lane group covers 64 contiguous k = one k-tile
        if ((lane & 15) == 0) {
            unsigned m16 = (unsigned)(bal >> (g * 16)) & 0xFFFFu;
            if (m16 != 0xFFFFu) {
                int b = i >> 22;               // SEQ*SEQ = 2^22
                int rem = i & 4194303;
                int q = rem >> 11, k = rem & 2047;
                atomicAnd(&flags[(b << 10) + ((q >> 6) << 5) + (k >> 6)], 0);
            }
        }
        return;
    }
    const float* src;
    unsigned short* dst;
    int base;
    float scale = 1.0f;
    if (id < 4096)       { src = xq; dst = dxq; base = 0; }
    else if (id < 8192)  { src = xk; dst = dxk; base = 4096; }
    else if (id < 9216)  { src = Wq; dst = dwq; base = 8192; scale = QSCALE; }
    else if (id < 10240) { src = Wk; dst = dwk; base = 9216; }
    else                 { src = Wv; dst = dwv; base = 10240; }
    int i = ((id - base) * 256 + threadIdx.x) * 4;
    float4 v = *(const float4*)(src + i);
    ushort4 o;
    o.x = f2bf(v.x * scale); o.y = f2bf(v.y * scale);
    o.z = f2bf(v.z * scale); o.w = f2bf(v.w * scale);
    *(ushort4*)(dst + i) = o;
}

// ---------------- QKV projection GEMMs (round-10 proven config, restored) ----------
// 768 blocks (flat XCD-swizzled = 3 blocks/CU = 12 waves/CU), 128x128 tile,
// 4 waves, BK=32, 3-buffer rotation with counted vmcnt(4) + raw s_barrier.
// XOR-swizzled LDS. [Local optimum: 5 structural alternatives all regressed.]
__global__ __launch_bounds__(256, 3) void proj_gemm(
    const unsigned short* __restrict__ xq, const unsigned short* __restrict__ xk,
    const unsigned short* __restrict__ wq, const unsigned short* __restrict__ wk,
    const unsigned short* __restrict__ wv,
    const float* __restrict__ bq, const float* __restrict__ bk, const float* __restrict__ bv,
    unsigned short* __restrict__ Qh, unsigned short* __restrict__ Kh,
    unsigned short* __restrict__ Vt) {
    __shared__ __align__(16) unsigned short As[3][128 * 32];   // 24 KB
    __shared__ __align__(16) unsigned short Bs[3][128 * 32];   // 24 KB

    const int id = blockIdx.x;
    const int xid = (id & 7) * 96 + (id >> 3);   // 768 = 8*96, bijective XCD swizzle
    const unsigned short *A, *B;
    const float* bias;
    float bsc = 1.0f;
    unsigned short* out;
    int mt, nt;
    bool tr = false;
    if (xid < 256)      { A = xq; B = wq; bias = bq; bsc = QSCALE; out = Qh;
                          mt = xid >> 3; nt = xid & 7; }
    else if (xid < 512) { A = xk; B = wk; bias = bk; out = Kh;
                          mt = (xid - 256) >> 3; nt = (xid - 256) & 7; }
    else                { A = wv; B = xk; bias = bv; out = Vt; tr = true;
                          mt = (xid - 512) & 7; nt = (xid - 512) >> 3; }
    const int m0 = mt * 128, n0 = nt * 128;
    const int tid = threadIdx.x, wave = tid >> 6, lane = tid & 63;
    const int wr = (wave >> 1) * 64, wc = (wave & 1) * 64;
    const int fr = lane & 15, hi = lane >> 4;

    const int uswz = (hi ^ ((fr >> 1) & 3)) << 3;
    const int abase = (wr + fr) * 32 + uswz;
    const int bbase = (wc + fr) * 32 + uswz;

    const int srow = wave * 16 + (lane >> 2);
    const int sunit = (lane & 3) ^ ((lane >> 3) & 3);
    const unsigned short* Asrc = A + (size_t)(m0 + srow) * HID + sunit * 8;
    const unsigned short* Bsrc = B + (size_t)(n0 + srow) * HID + sunit * 8;

    unsigned short *cA = As[0], *nA = As[1], *fA = As[2];
    unsigned short *cB = Bs[0], *nB = Bs[1], *fB = Bs[2];

    f32x4 acc[4][4] = {};

#define PSTG(t, ap, bp)                                                          \
    do {                                                                         \
        gload_lds16(Asrc + (t) * 32, (ap) + wave * 512);                         \
        gload_lds16(Asrc + (size_t)64 * HID + (t) * 32, (ap) + 2048 + wave * 512); \
        gload_lds16(Bsrc + (t) * 32, (bp) + wave * 512);                         \
        gload_lds16(Bsrc + (size_t)64 * HID + (t) * 32, (bp) + 2048 + wave * 512); \
    } while (0)

    PSTG(0, cA, cB);
    PSTG(1, nA, nB);

    for (int t = 0; t < 32; ++t) {
        if (t < 31) asm volatile("s_waitcnt vmcnt(4)" ::: "memory");  // own stage(t) done
        else        asm volatile("s_waitcnt vmcnt(0)" ::: "memory");
        __builtin_amdgcn_s_barrier();      // everyone's stage(t) landed; buf(t-1) free
        if (t < 30) PSTG(t + 2, fA, fB);   // into the buffer read at t-1

        bf16x8 af[4], bfr[4];
#pragma unroll
        for (int i = 0; i < 4; ++i) af[i] = *(const bf16x8*)&cA[abase + i * 512];
#pragma unroll
        for (int j = 0; j < 4; ++j) bfr[j] = *(const bf16x8*)&cB[bbase + j * 512];
        __builtin_amdgcn_s_setprio(1);
#pragma unroll
        for (int i = 0; i < 4; ++i)
#pragma unroll
            for (int j = 0; j < 4; ++j)
                acc[i][j] = MFMA16(af[i], bfr[j], acc[i][j]);
        __builtin_amdgcn_s_setprio(0);

        unsigned short* ta = cA; cA = nA; nA = fA; fA = ta;
        unsigned short* tb = cB; cB = nB; nB = fB; fB = tb;
    }
#undef PSTG

#pragma unroll
    for (int i = 0; i < 4; ++i)
#pragma unroll
        for (int j = 0; j < 4; ++j)
#pragma unroll
            for (int r = 0; r < 4; ++r) {
                int row = m0 + wr + i * 16 + hi * 4 + r;   // C/D: row=(lane>>4)*4+reg
                int col = n0 + wc + j * 16 + fr;           //      col=lane&15
                float v = acc[i][j][r];
                if (!tr) {
                    v += bsc * bias[col];
                    int b = row >> 11, l = row & 2047, hh = col >> 6, d = col & 63;
                    out[(((size_t)(b * NH + hh)) * SEQ + l) * HD + d] = f2bf(v);
                } else {
                    v += bias[row];
                    int b = col >> 11, ll = col & 2047, hh = row >> 6, d = row & 63;
                    // sigma: slot-permute k within each 64-block so flash's PV B-frags
                    // are the lane-local cvtpk outputs
                    int lp = (ll & ~0x1C) | ((ll & 0x0C) << 1) | ((ll & 0x10) >> 2);
                    out[(((size_t)(b * NH + hh)) * HD + d) * SEQ + lp] = f2bf(v);
                }
            }
}

// ---------------- flash attention (R10 + hoisted mask branch) ----------------
// grid 512 (XCD-clustered bh), 4 waves x 32 q (dual Q-group). 4-buffer K/V ring,
// ONE barrier per 2 tiles. The per-tile mask test is hoisted out of the K-loop:
// bm==~0 (always here) selects a branch-FREE loop whose 2-tile intervals are
// single basic blocks — lets the scheduler overlap tile-b QK with tile-a
// softmax/PV (the branches were blocking the cross-tile scheduling the pairing
// was designed for). Slow path = R10 FTILE verbatim; identical barrier counts.
__global__ __launch_bounds__(256, 2) void flash_attn(
    const unsigned short* __restrict__ Qh, const unsigned short* __restrict__ Kh,
    const unsigned short* __restrict__ Vt, const float* __restrict__ mask,
    const int* __restrict__ flags, float* __restrict__ out) {
    __shared__ __align__(16) unsigned short Ks[4][64 * 64];   // 32 KB, unit^=(row&7)
    __shared__ __align__(16) unsigned short Vs[4][64 * 64];   // 32 KB, same swizzle

    const int tid = threadIdx.x, wave = tid >> 6, lane = tid & 63;
    const int id = blockIdx.x;                       // 0..511
    const int bh = (id & 7) * 4 + ((id >> 3) & 3);   // XCD-clustered
    const int qi = id >> 5;                          // 128-q tile index 0..15
    const int b = bh >> 4, h = bh & 15;
    const size_t hoff = (size_t)bh * SEQ * HD;
    const int fr = lane & 15, hi = lane >> 4;
    const int f7 = fr & 7, swz3 = f7 << 3;
    const int qa = qi * 128 + wave * 32 + fr;
    const int qb = qa + 16;

    // Q B-frags for both groups (col = q = lane&15, contraction d = hi*8..)
    bf16x8 qfa0 = *(const bf16x8*)&Qh[hoff + (size_t)qa * HD + hi * 8];
    bf16x8 qfa1 = *(const bf16x8*)&Qh[hoff + (size_t)qa * HD + 32 + hi * 8];
    bf16x8 qfb0 = *(const bf16x8*)&Qh[hoff + (size_t)qb * HD + hi * 8];
    bf16x8 qfb1 = *(const bf16x8*)&Qh[hoff + (size_t)qb * HD + 32 + hi * 8];

    const float* mrowA = mask + (size_t)b * SEQ * SEQ + (size_t)qa * SEQ;
    const float* mrowB = mask + (size_t)b * SEQ * SEQ + (size_t)qb * SEQ;
    // this wave's 64-q tile = qi*2 + (wave>>1)
    const int* frow = flags + (b << 10) + ((qi * 2 + (wave >> 1)) << 5);
    int fv = frow[lane & 31];
    const unsigned long long bm = __ballot(fv != 0);   // bit t: tile t all-ones

    // staging: linear LDS dest, inverse-swizzled global source
    const int srow = wave * 8 + (lane >> 3);
    const int sch = (lane & 7) ^ (srow & 7);
    const unsigned short* kbase = Kh + hoff + (size_t)srow * HD + (sch << 3);
    const unsigned short* vbase = Vt + hoff + (size_t)srow * SEQ + (sch << 3);

    f32x4 accA[4] = {}, accB[4] = {};
    f32x4 laccA = {}, laccB = {};
    const bf16x8 ones = {0x3F80, 0x3F80, 0x3F80, 0x3F80, 0x3F80, 0x3F80, 0x3F80, 0x3F80};

#define STG(t, kd, vd)                                                           \
    do {                                                                         \
        gload_lds16(kbase + (size_t)(t) * 64 * HD, (kd) + (wave * 8) * 64);      \
        gload_lds16(kbase + (size_t)((t) * 64 + 32) * HD, (kd) + (wave * 8 + 32) * 64); \
        gload_lds16(vbase + (t) * 64, (vd) + (wave * 8) * 64);                   \
        gload_lds16(vbase + (size_t)32 * SEQ + (t) * 64, (vd) + (wave * 8 + 32) * 64); \
    } while (0)

// QK + optional mask + softmax + PV for one 64-k tile. M = 0: branch-free.
#define FTILE_M(kd, vd, tt, M)                                                   \
    do {                                                                         \
        f32x4 sA[4], sB[4];                                                      \
        __builtin_amdgcn_s_setprio(1);                                           \
        _Pragma("unroll")                                                        \
        for (int sub = 0; sub < 4; ++sub) {                                      \
            const int rbase = (sub * 16 + fr) * 64;                              \
            bf16x8 kf0 = *(const bf16x8*)&(kd)[rbase + ((hi << 3) ^ swz3)];      \
            bf16x8 kf1 = *(const bf16x8*)&(kd)[rbase + (((hi + 4) << 3) ^ swz3)]; \
            f32x4 z = {0.f, 0.f, 0.f, 0.f};                                      \
            z = MFMA16(kf0, qfa0, z);                                            \
            z = MFMA16(kf1, qfa1, z);                                            \
            sA[sub] = z;                                                         \
            f32x4 w = {0.f, 0.f, 0.f, 0.f};                                      \
            w = MFMA16(kf0, qfb0, w);                                            \
            w = MFMA16(kf1, qfb1, w);                                            \
            sB[sub] = w;                                                         \
        }                                                                        \
        __builtin_amdgcn_s_setprio(0);                                           \
        if (M && !((bm >> (tt)) & 1)) {   /* raw f32 fallback */                 \
            const int k0 = (tt) * 64;                                            \
            _Pragma("unroll")                                                    \
            for (int sub = 0; sub < 4; ++sub) {                                  \
                float4 ma = *(const float4*)&mrowA[k0 + sub * 16 + hi * 4];      \
                sA[sub][0] += (1.f - ma.x) * (-10000.f * MASKSCALE);             \
                sA[sub][1] += (1.f - ma.y) * (-10000.f * MASKSCALE);             \
                sA[sub][2] += (1.f - ma.z) * (-10000.f * MASKSCALE);             \
                sA[sub][3] += (1.f - ma.w) * (-10000.f * MASKSCALE);             \
                float4 mv = *(const float4*)&mrowB[k0 + sub * 16 + hi * 4];      \
                sB[sub][0] += (1.f - mv.x) * (-10000.f * MASKSCALE);             \
                sB[sub][1] += (1.f - mv.y) * (-10000.f * MASKSCALE);             \
                sB[sub][2] += (1.f - mv.z) * (-10000.f * MASKSCALE);             \
                sB[sub][3] += (1.f - mv.w) * (-10000.f * MASKSCALE);             \
            }                                                                    \
        }                                                                        \
        _Pragma("unroll")                                                        \
        for (int sub = 0; sub < 4; ++sub)                                        \
            _Pragma("unroll")                                                    \
            for (int r = 0; r < 4; ++r) {                                        \
                sA[sub][r] = __builtin_amdgcn_exp2f(sA[sub][r]);                 \
                sB[sub][r] = __builtin_amdgcn_exp2f(sB[sub][r]);                 \
            }                                                                    \
        u32x4 wa0, wa1, wb0, wb1;                                                \
        wa0[0] = cvtpk(sA[0][0], sA[0][1]); wa0[1] = cvtpk(sA[0][2], sA[0][3]);  \
        wa0[2] = cvtpk(sA[1][0], sA[1][1]); wa0[3] = cvtpk(sA[1][2], sA[1][3]);  \
        wa1[0] = cvtpk(sA[2][0], sA[2][1]); wa1[1] = cvtpk(sA[2][2], sA[2][3]);  \
        wa1[2] = cvtpk(sA[3][0], sA[3][1]); wa1[3] = cvtpk(sA[3][2], sA[3][3]);  \
        wb0[0] = cvtpk(sB[0][0], sB[0][1]); wb0[1] = cvtpk(sB[0][2], sB[0][3]);  \
        wb0[2] = cvtpk(sB[1][0], sB[1][1]); wb0[3] = cvtpk(sB[1][2], sB[1][3]);  \
        wb1[0] = cvtpk(sB[2][0], sB[2][1]); wb1[1] = cvtpk(sB[2][2], sB[2][3]);  \
        wb1[2] = cvtpk(sB[3][0], sB[3][1]); wb1[3] = cvtpk(sB[3][2], sB[3][3]);  \
        bf16x8 pA0 = __builtin_bit_cast(bf16x8, wa0);                            \
        bf16x8 pA1 = __builtin_bit_cast(bf16x8, wa1);                            \
        bf16x8 pB0 = __builtin_bit_cast(bf16x8, wb0);                            \
        bf16x8 pB1 = __builtin_bit_cast(bf16x8, wb1);                            \
        __builtin_amdgcn_s_setprio(1);                                           \
        laccA = MFMA16(ones, pA0, laccA);                                        \
        laccA = MFMA16(ones, pA1, laccA);                                        \
        laccB = MFMA16(ones, pB0, laccB);                                        \
        laccB = MFMA16(ones, pB1, laccB);                                        \
        _Pragma("unroll")                                                        \
        for (int sub = 0; sub < 4; ++sub) {                                      \
            const int rbase = (sub * 16 + fr) * 64;                              \
            bf16x8 vf0 = *(const bf16x8*)&(vd)[rbase + ((hi << 3) ^ swz3)];      \
            bf16x8 vf1 = *(const bf16x8*)&(vd)[rbase + (((hi + 4) << 3) ^ swz3)]; \
            accA[sub] = MFMA16(vf0, pA0, accA[sub]);                             \
            accA[sub] = MFMA16(vf1, pA1, accA[sub]);                             \
            accB[sub] = MFMA16(vf0, pB0, accB[sub]);                             \
            accB[sub] = MFMA16(vf1, pB1, accB[sub]);                             \
        }                                                                        \
        __builtin_amdgcn_s_setprio(0);                                           \
    } while (0)

#define MAINLOOP(M)                                                              \
    for (int ii = 0; ii < 8; ++ii) {                                             \
        const int t0 = ii * 4;                                                   \
        asm volatile("s_waitcnt vmcnt(0)" ::: "memory");                         \
        __builtin_amdgcn_s_barrier();                                            \
        STG(t0 + 2, Ks[2], Vs[2]);                                               \
        STG(t0 + 3, Ks[3], Vs[3]);                                               \
        FTILE_M(Ks[0], Vs[0], t0, M);                                            \
        FTILE_M(Ks[1], Vs[1], t0 + 1, M);                                        \
        asm volatile("s_waitcnt vmcnt(0)" ::: "memory");                         \
        __builtin_amdgcn_s_barrier();                                            \
        if (ii < 7) {                                                            \
            STG(t0 + 4, Ks[0], Vs[0]);                                           \
            STG(t0 + 5, Ks[1], Vs[1]);                                           \
        }                                                                        \
        FTILE_M(Ks[2], Vs[2], t0 + 2, M);                                        \
        FTILE_M(Ks[3], Vs[3], t0 + 3, M);                                        \
    }

    STG(0, Ks[0], Vs[0]);
    STG(1, Ks[1], Vs[1]);

    if (bm == ~0ULL) {
        MAINLOOP(0)   // branch-free fast path (always taken for all-ones mask)
    } else {
        MAINLOOP(1)   // masked path, R10-verbatim semantics
    }
#undef MAINLOOP
#undef STG
#undef FTILE_M

    // epilogue
    float rA = 1.0f / laccA[0], rB = 1.0f / laccB[0];
#pragma unroll
    for (int sub = 0; sub < 4; ++sub) {
        float4 oA = {accA[sub][0] * rA, accA[sub][1] * rA, accA[sub][2] * rA, accA[sub][3] * rA};
        *(float4*)&out[((size_t)b * SEQ + qa) * HID + h * HD + sub * 16 + hi * 4] = oA;
        float4 oB = {accB[sub][0] * rB, accB[sub][1] * rB, accB[sub][2] * rB, accB[sub][3] * rB};
        *(float4*)&out[((size_t)b * SEQ + qb) * HID + h * HD + sub * 16 + hi * 4] = oB;
    }
}

// ---------------- launcher ----------------
extern "C" void kernel_launch(void* const* d_in, const int* in_sizes, int n_in,
                              void* d_out, int out_size, void* d_ws, size_t ws_size,
                              hipStream_t stream) {
    const float* xq = (const float*)d_in[0];
    const float* xk = (const float*)d_in[1];
    const float* mask = (const float*)d_in[2];
    const float* Wq = (const float*)d_in[3];
    const float* bq = (const float*)d_in[4];
    const float* Wk = (const float*)d_in[5];
    const float* bk = (const float*)d_in[6];
    const float* Wv = (const float*)d_in[7];
    const float* bv = (const float*)d_in[8];
    float* out = (float*)d_out;

    const size_t NX = (size_t)NTOK * HID;      // 4,194,304
    const size_t NW = (size_t)HID * HID;       // 1,048,576
    const size_t need = (5 * NX + 3 * NW) * sizeof(unsigned short) + 2048 * sizeof(int);
    if (ws_size < need) return;

    unsigned short* ws = (unsigned short*)d_ws;
    unsigned short* xq_b = ws;
    unsigned short* xk_b = xq_b + NX;
    unsigned short* wq_b = xk_b + NX;
    unsigned short* wk_b = wq_b + NW;
    unsigned short* wv_b = wk_b + NW;
    unsigned short* Qh = wv_b + NW;
    unsigned short* Kh = Qh + NX;
    unsigned short* Vt = Kh + NX;
    int* flags = (int*)(Vt + NX);

    hipMemsetAsync(flags, 0xFF, 2048 * sizeof(int), stream);
    cvt_all<<<19456, 256, 0, stream>>>(xq, xk, Wq, Wk, Wv, mask,
                                       xq_b, xk_b, wq_b, wk_b, wv_b, flags);
    proj_gemm<<<768, 256, 0, stream>>>(xq_b, xk_b, wq_b, wk_b, wv_b,
                                       bq, bk, bv, Qh, Kh, Vt);
    flash_attn<<<512, 256, 0, stream>>>(Qh, Kh, Vt, mask, flags, out);
}